// Round 5
// baseline (467.600 us; speedup 1.0000x reference)
//
#include <hip/hip_runtime.h>
#include <math.h>

// Problem constants
#define TTOK   16384
#define HDIM   4096
#define ENUM   64
#define KTOP   6
#define GNUM   8
#define TGK    3
#define BBATCH 4
#define SSEQ   4096
#define ALPHAC 0.001f

// GEMM tiling
#define KSPLIT 4
#define KSL    (HDIM / KSPLIT)   // 1024 k per slice
#define TM     128               // tokens per block
#define BK     64                // k per LDS iter -> 256-B rows, 16-slot XOR (conflict-free)
#define NIT    (KSL / BK)        // 16 iterations

#define AS3(p) ((__attribute__((address_space(3))) void*)(p))
#define AS1(p) ((const __attribute__((address_space(1))) void*)(p))

typedef float wvec16 __attribute__((ext_vector_type(16)));

// ---------------------------------------------------------------------------
// Kernel 0: pack W[64][4096] -> Wp[k4][e][4]  (k-chunks of 4, expert-major)
// a wave's per-kq W slice (8 experts x 4 k) is 128 B contiguous -> 2x s_load_dwordx16
// ---------------------------------------------------------------------------
__global__ __launch_bounds__(256)
void pack_w(const float* __restrict__ W, float* __restrict__ Wp) {
    const int gid = blockIdx.x * 256 + threadIdx.x;   // 0..65535
    const int k4 = gid >> 6, e = gid & 63;
    float4 v = *(const float4*)(W + (size_t)e * HDIM + k4 * 4);
    *(float4*)(Wp + (size_t)gid * 4) = v;
}

// ---------------------------------------------------------------------------
// Kernel 1: gate GEMM. Block = 128 tokens x ALL 64 experts, 8 waves.
// Wave w: experts 8w..8w+7; lane holds 2 tokens (acc[2][8]).
// BK=64 -> LDS rows are 256 B with a 16-slot XOR swizzle: in every 16-lane
// b128 phase the 16 lanes read 16 DISTINCT 16-B slots = all 32 banks exactly
// 2x = conflict-free (round-0 layout, counter-verified 0 conflicts).
// W: 128 B/kq wave-uniform s_load, explicitly double-buffered in registers
// (kq+1's loads issue before kq's fmacs) to hide SMEM latency.
// Classic 2-buffer __syncthreads loop: per-iter compute (~2048 cyc) >> load
// latency, so the barrier vmcnt drain is free (round-4 lesson).
// ---------------------------------------------------------------------------
__global__ __launch_bounds__(512, 4)
void gate_gemm(const float* __restrict__ X, const float* __restrict__ Wp,
               float* __restrict__ lp) {
    __shared__ __align__(16) float Xs[2][TM * BK];   // 2 x 32 KB -> 2 blocks/CU

    const int tid  = threadIdx.x;
    const int w    = __builtin_amdgcn_readfirstlane(tid >> 6);  // wave 0..7
    const int l    = tid & 63;
    const int lm15 = l & 15;

    const int id    = blockIdx.x;                  // 0..511 (= 2 per CU exactly)
    const int tile  = id >> 2;                     // 0..127
    const int slice = id & 3;                      // 0..3
    const int T0    = tile * TM;
    const int k0    = slice * KSL;
    const int E0    = w * 8;                       // this wave's 8 experts

    // staging: wave w owns rows 16w..16w+15 (4 calls x 4 rows x 1024 B).
    // Call r: lane l writes LDS byte (w*16+r*4)*256 + l*16
    //   -> row t = w*16 + r*4 + (l>>4), slot s = l&15.
    // Slot s of row t must hold global k4-chunk s ^ (t&15); t&15 = r*4+(l>>4)
    //   -> pre-swizzled per-lane SOURCE, linear LDS dest (rule #21).
    const int rl = l >> 4;                         // 0..3
    const float* gsp[4];
#pragma unroll
    for (int r = 0; r < 4; ++r)
        gsp[r] = X + (size_t)(T0 + w * 16 + r * 4 + rl) * HDIM + k0
               + ((lm15 ^ (r * 4 + rl)) << 2);

#define STAGE(buf_, it_) do {                                                   \
    const size_t go_ = (size_t)(it_) * BK;                                      \
    _Pragma("unroll")                                                           \
    for (int r_ = 0; r_ < 4; ++r_)                                              \
        __builtin_amdgcn_global_load_lds(AS1(gsp[r_] + go_),                    \
            AS3(&Xs[buf_][(w * 16 + r_ * 4) * BK]), 16, 0, 0);                  \
} while (0)

    float acc[2][8];
#pragma unroll
    for (int g = 0; g < 2; ++g)
#pragma unroll
        for (int j = 0; j < 8; ++j) acc[g][j] = 0.f;

    const int k4base = k0 >> 2;

    STAGE(0, 0);   // prologue

    for (int it = 0; it < NIT; ++it) {
        __syncthreads();   // drains this iter's staging (free: compute >> latency)
        if (it + 1 < NIT) STAGE((it + 1) & 1, it + 1);

        const float* xb = Xs[it & 1];
        const int k4it  = k4base + it * (BK / 4);

        // W register double-buffer: load kq=0, then in the unrolled loop issue
        // kq+1's 2 s_load_dwordx16 BEFORE kq's 128 fmac cycles.
        wvec16 wA[2], wB[2];
        {
            const float* wp = Wp + ((size_t)k4it * ENUM + E0) * 4;
            wA[0] = *(const wvec16*)(wp);
            wB[0] = *(const wvec16*)(wp + 16);
        }
#pragma unroll
        for (int kq = 0; kq < 16; ++kq) {
            const int cur = kq & 1, nxt = cur ^ 1;   // compile-time after unroll
            if (kq + 1 < 16) {
                const float* wp = Wp + ((size_t)(k4it + kq + 1) * ENUM + E0) * 4;
                wA[nxt] = *(const wvec16*)(wp);
                wB[nxt] = *(const wvec16*)(wp + 16);
            }
            const int slot = (kq ^ lm15) << 2;       // swizzled float4 slot
#pragma unroll
            for (int g = 0; g < 2; ++g) {
                const float4 xv = *(const float4*)(xb + (g * 64 + l) * BK + slot);
#pragma unroll
                for (int j = 0; j < 4; ++j) {
                    acc[g][j] = fmaf(xv.x, wA[cur][4 * j + 0], acc[g][j]);
                    acc[g][j] = fmaf(xv.y, wA[cur][4 * j + 1], acc[g][j]);
                    acc[g][j] = fmaf(xv.z, wA[cur][4 * j + 2], acc[g][j]);
                    acc[g][j] = fmaf(xv.w, wA[cur][4 * j + 3], acc[g][j]);
                }
#pragma unroll
                for (int j = 0; j < 4; ++j) {
                    acc[g][4 + j] = fmaf(xv.x, wB[cur][4 * j + 0], acc[g][4 + j]);
                    acc[g][4 + j] = fmaf(xv.y, wB[cur][4 * j + 1], acc[g][4 + j]);
                    acc[g][4 + j] = fmaf(xv.z, wB[cur][4 * j + 2], acc[g][4 + j]);
                    acc[g][4 + j] = fmaf(xv.w, wB[cur][4 * j + 3], acc[g][4 + j]);
                }
            }
        }
    }

    float* dst = lp + (size_t)slice * TTOK * ENUM + (size_t)(T0 + l) * ENUM + E0;
#pragma unroll
    for (int g = 0; g < 2; ++g) {
        float* d = dst + (size_t)g * 64 * ENUM;
        *(float4*)(d + 0) = make_float4(acc[g][0], acc[g][1], acc[g][2], acc[g][3]);
        *(float4*)(d + 4) = make_float4(acc[g][4], acc[g][5], acc[g][6], acc[g][7]);
    }
#undef STAGE
}

// ---------------------------------------------------------------------------
// Kernel 2: thread-per-token router. 64 tokens/block, 256 blocks.
// (generic over KSPLIT partials)
// ---------------------------------------------------------------------------
#define RTOK 64
__global__ __launch_bounds__(256)
void router_topk(const float* __restrict__ lp,
                 float* __restrict__ out_idx, float* __restrict__ out_w,
                 float* __restrict__ ssum_g, int* __restrict__ cnt_g) {
    __shared__ float Ls[RTOK * 67];
    __shared__ float s_m[RTOK], s_inv[RTOK];
    __shared__ float s_ssum[ENUM];
    __shared__ int   s_cnt[ENUM];

    const int tid = threadIdx.x;
    const int t0  = blockIdx.x * RTOK;
    if (tid < ENUM) { s_cnt[tid] = 0; s_ssum[tid] = 0.f; }

#pragma unroll
    for (int r = 0; r < 4; ++r) {
        const int q  = r * 256 + tid;
        const int t  = q >> 4, c4 = q & 15;
        const size_t base = (size_t)(t0 + t) * ENUM + c4 * 4;
        float4 v = *(const float4*)(lp + base);
#pragma unroll
        for (int h = 1; h < KSPLIT; ++h) {
            float4 u = *(const float4*)(lp + (size_t)h * TTOK * ENUM + base);
            v.x += u.x; v.y += u.y; v.z += u.z; v.w += u.w;
        }
        float* d = Ls + t * 67 + c4 * 4;
        d[0] = v.x; d[1] = v.y; d[2] = v.z; d[3] = v.w;
    }
    __syncthreads();

    if (tid < RTOK) {
        const float* row = Ls + tid * 67;

        float gm[GNUM];
#pragma unroll
        for (int g = 0; g < GNUM; ++g) {
            float mg = row[g * 8];
#pragma unroll
            for (int j = 1; j < 8; ++j) mg = fmaxf(mg, row[g * 8 + j]);
            gm[g] = mg;
        }
        float m = gm[0];
#pragma unroll
        for (int g = 1; g < GNUM; ++g) m = fmaxf(m, gm[g]);

        int selmask = 0;
#pragma unroll
        for (int g = 0; g < GNUM; ++g) {
            int rank = 0;
#pragma unroll
            for (int g2 = 0; g2 < GNUM; ++g2)
                rank += (gm[g2] > gm[g]) || (gm[g2] == gm[g] && g2 < g);
            selmask |= (rank < TGK) << g;
        }

        float v0=-1.f,v1=-1.f,v2=-1.f,v3=-1.f,v4=-1.f,v5=-1.f;
        float i0=0.f,i1=0.f,i2=0.f,i3=0.f,i4=0.f,i5=0.f;
        float s = 0.f;
#pragma unroll
        for (int e = 0; e < ENUM; ++e) {
            const float ex = __expf(row[e] - m);
            s += ex;
            const float cand = ((selmask >> (e >> 3)) & 1) ? ex : -1.0f;
            const float fe = (float)e;
            const bool b0 = cand > v0, b1 = cand > v1, b2 = cand > v2,
                       b3 = cand > v3, b4 = cand > v4, b5 = cand > v5;
            v5 = b4 ? v4 : (b5 ? cand : v5);  i5 = b4 ? i4 : (b5 ? fe : i5);
            v4 = b3 ? v3 : (b4 ? cand : v4);  i4 = b3 ? i3 : (b4 ? fe : i4);
            v3 = b2 ? v2 : (b3 ? cand : v3);  i3 = b2 ? i2 : (b3 ? fe : i3);
            v2 = b1 ? v1 : (b2 ? cand : v2);  i2 = b1 ? i1 : (b2 ? fe : i2);
            v1 = b0 ? v0 : (b1 ? cand : v1);  i1 = b0 ? i0 : (b1 ? fe : i1);
            v0 = b0 ? cand : v0;              i0 = b0 ? fe : i0;
        }
        const float invw = 1.0f / (v0 + v1 + v2 + v3 + v4 + v5);
        const int t = t0 + tid;
        float* oi = out_idx + (size_t)t * KTOP;
        float* ow = out_w   + (size_t)t * KTOP;
        oi[0]=i0; oi[1]=i1; oi[2]=i2; oi[3]=i3; oi[4]=i4; oi[5]=i5;
        ow[0]=v0*invw; ow[1]=v1*invw; ow[2]=v2*invw;
        ow[3]=v3*invw; ow[4]=v4*invw; ow[5]=v5*invw;

        atomicAdd(&s_cnt[(int)i0], 1); atomicAdd(&s_cnt[(int)i1], 1);
        atomicAdd(&s_cnt[(int)i2], 1); atomicAdd(&s_cnt[(int)i3], 1);
        atomicAdd(&s_cnt[(int)i4], 1); atomicAdd(&s_cnt[(int)i5], 1);
        s_m[tid] = m; s_inv[tid] = 1.0f / s;
    }
    __syncthreads();

    {
        const int e = tid & 63, strip = tid >> 6;
        float acc = 0.f;
#pragma unroll
        for (int i = 0; i < RTOK / 4; ++i) {
            const int t = strip * (RTOK / 4) + i;
            acc += __expf(Ls[t * 67 + e] - s_m[t]) * s_inv[t];
        }
        atomicAdd(&s_ssum[e], acc);
    }
    __syncthreads();

    const int b = t0 / SSEQ;
    if (tid < ENUM) {
        atomicAdd(&ssum_g[b * ENUM + tid], s_ssum[tid]);
        atomicAdd(&cnt_g[b * ENUM + tid], s_cnt[tid]);
    }
}

// ---------------------------------------------------------------------------
// Kernel 3: aux loss (1 block) (unchanged)
// ---------------------------------------------------------------------------
__global__ __launch_bounds__(256)
void aux_loss(const float* __restrict__ ssum_g, const int* __restrict__ cnt_g,
              float* __restrict__ out_aux) {
    const int tid = threadIdx.x;
    float v = (float)cnt_g[tid] * (float)ENUM / ((float)SSEQ * (float)KTOP)
            * (ssum_g[tid] / (float)SSEQ);
#pragma unroll
    for (int off = 32; off; off >>= 1) v += __shfl_xor(v, off);
    __shared__ float red[4];
    if ((tid & 63) == 0) red[tid >> 6] = v;
    __syncthreads();
    if (tid == 0)
        out_aux[0] = (red[0] + red[1] + red[2] + red[3]) * (ALPHAC / (float)BBATCH);
}

// ---------------------------------------------------------------------------
extern "C" void kernel_launch(void* const* d_in, const int* in_sizes, int n_in,
                              void* d_out, int out_size, void* d_ws, size_t ws_size,
                              hipStream_t stream) {
    const float* X = (const float*)d_in[0];   // [4,4096,4096] fp32
    const float* W = (const float*)d_in[1];   // [64,4096] fp32

    float* out     = (float*)d_out;
    float* out_idx = out;
    float* out_w   = out + (size_t)TTOK * KTOP;
    float* out_aux = out + (size_t)2 * TTOK * KTOP;

    float* lp     = (float*)d_ws;                        // [4][T][64] = 16 MiB
    float* Wp     = lp + (size_t)KSPLIT * TTOK * ENUM;   // [1024][64][4] = 1 MiB
    float* ssum_g = Wp + (size_t)HDIM * ENUM;            // [4][64]
    int*   cnt_g  = (int*)(ssum_g + BBATCH * ENUM);      // [4][64]

    hipMemsetAsync(ssum_g, 0, BBATCH * ENUM * (sizeof(float) + sizeof(int)), stream);

    pack_w<<<(HDIM / 4) * ENUM / 256, 256, 0, stream>>>(W, Wp);
    gate_gemm<<<(TTOK / TM) * KSPLIT, 512, 0, stream>>>(X, Wp, lp);
    router_topk<<<TTOK / RTOK, 256, 0, stream>>>(lp, out_idx, out_w, ssum_g, cnt_g);
    aux_loss<<<1, 256, 0, stream>>>(ssum_g, cnt_g, out_aux);
}

// Round 6
// 458.544 us; speedup vs baseline: 1.0197x; 1.0197x over previous
//
#include <hip/hip_runtime.h>
#include <math.h>

// Problem constants
#define TTOK   16384
#define HDIM   4096
#define ENUM   64
#define KTOP   6
#define GNUM   8
#define TGK    3
#define BBATCH 4
#define SSEQ   4096
#define ALPHAC 0.001f

// GEMM tiling
#define KSPLIT 4
#define KSL    (HDIM / KSPLIT)   // 1024 k per slice
#define TM     128               // tokens per block
#define TE     32                // experts per block (eh half of 64)
#define BK     64                // k per LDS iter -> 256-B X rows, 16-slot XOR (0-conflict, verified)
#define NIT    (KSL / BK)        // 16 iterations

#define AS3(p) ((__attribute__((address_space(3))) void*)(p))
#define AS1(p) ((const __attribute__((address_space(1))) void*)(p))

// ---------------------------------------------------------------------------
// Kernel 0: pack W[64][4096] -> Wp[k4][e][4]  (k-chunks of 4, expert-major)
// ---------------------------------------------------------------------------
__global__ __launch_bounds__(256)
void pack_w(const float* __restrict__ W, float* __restrict__ Wp) {
    const int gid = blockIdx.x * 256 + threadIdx.x;   // 0..65535
    const int k4 = gid >> 6, e = gid & 63;
    float4 v = *(const float4*)(W + (size_t)e * HDIM + k4 * 4);
    *(float4*)(Wp + (size_t)gid * 4) = v;
}

// ---------------------------------------------------------------------------
// Kernel 1: gate GEMM. Block = 256 thr (4 waves) = 128 tokens x 32 experts.
// Wave w: local experts 8w..8w+7; lane holds 2 tokens (acc[2][8]).
//
// KEY CHANGE vs rounds 0-5: NO SMEM (s_load) IN THE INNER LOOP. W flows
// global -> LDS (global_load_lds) -> uniform-address ds_read_b128 broadcast.
// Rationale: s_load and ds_read share lgkmcnt, and SMEM completes out of
// order, so any use of ds_read data with s_loads outstanding forces
// s_waitcnt lgkmcnt(0) (full drain incl. prefetches) -- one exposed SMEM
// latency per kq, capping VALUBusy at ~30-39% in every prior round.
// Pure-DS loops get counted lgkmcnt(N) from the compiler (m97 behavior).
//
// X LDS: BK=64 rows (256 B), 16-slot XOR swizzle -- counter-verified 0
// conflicts. W LDS reads are same-address broadcasts (free, m136).
// LDS = 2x32KB (X) + 2x8KB (W) = 80 KB -> 2 blocks/CU.
// ---------------------------------------------------------------------------
__global__ __launch_bounds__(256, 2)
void gate_gemm(const float* __restrict__ X, const float* __restrict__ Wp,
               float* __restrict__ lp) {
    __shared__ __align__(16) float Xs[2][TM * BK];      // 2 x 32 KB
    __shared__ __align__(16) float Ws[2][16 * TE * 4];  // 2 x 8 KB  [k4][e_loc][4]

    const int tid  = threadIdx.x;
    const int w    = tid >> 6;                 // wave 0..3
    const int l    = tid & 63;
    const int lm15 = l & 15;

    const int id    = blockIdx.x;              // 0..1023
    const int tile  = id >> 3;                 // 0..127
    const int eh    = (id >> 2) & 1;           // expert half
    const int slice = id & 3;                  // k slice
    const int T0    = tile * TM;
    const int k0    = slice * KSL;
    const int E0    = w * 8;                   // local expert base (within half)

    // X staging: call r (0..7), thread (w,l) writes chunk c = r*256 + w*64 + l
    // (16 B). Row t = c>>4 = r*16 + w*4 + (l>>4); slot s = c&15 = l&15.
    // Slot s of row t holds k4-chunk s ^ (t&15); t&15 = w*4 + (l>>4)
    // (r-independent) -> pre-swizzled per-lane SOURCE, linear LDS dest.
    const int rl = l >> 4;
    const int tb = w * 4 + rl;                 // t & 15
    const float* gx = X + (size_t)(T0 + tb) * HDIM + k0 + ((lm15 ^ tb) << 2);

    const int ehoff = eh * 128;                // float offset of half within k4-row

#define STAGE(buf_, it_) do {                                                   \
    const size_t go_ = (size_t)(it_) * BK;                                      \
    _Pragma("unroll")                                                           \
    for (int r_ = 0; r_ < 8; ++r_)                                              \
        __builtin_amdgcn_global_load_lds(                                       \
            AS1(gx + (size_t)r_ * 16 * HDIM + go_),                             \
            AS3(&Xs[buf_][(r_ * 256 + w * 64 + l) * 4]), 16, 0, 0);             \
    const int k4s_ = (k0 >> 2) + (it_) * 16;                                    \
    _Pragma("unroll")                                                           \
    for (int r_ = 0; r_ < 2; ++r_) {                                            \
        const int q_ = r_ * 256 + tid;                                          \
        __builtin_amdgcn_global_load_lds(                                       \
            AS1(Wp + (size_t)(k4s_ + (q_ >> 5)) * 256 + ehoff + (q_ & 31) * 4), \
            AS3(&Ws[buf_][q_ * 4]), 16, 0, 0);                                  \
    }                                                                           \
} while (0)

    float acc[2][8];
#pragma unroll
    for (int g = 0; g < 2; ++g)
#pragma unroll
        for (int j = 0; j < 8; ++j) acc[g][j] = 0.f;

    STAGE(0, 0);   // prologue

    for (int it = 0; it < NIT; ++it) {
        __syncthreads();   // drains this iter's staging (vmcnt) + barrier
        if (it + 1 < NIT) STAGE((it + 1) & 1, it + 1);

        const float* xb  = Xs[it & 1];
        const float* wsb = Ws[it & 1];
#pragma unroll
        for (int kq = 0; kq < 16; ++kq) {
            // 8 experts x 4 k of W: uniform-address ds_read_b128 broadcasts
            float4 wv[8];
#pragma unroll
            for (int j = 0; j < 8; ++j)
                wv[j] = *(const float4*)(wsb + (kq * TE + E0 + j) * 4);
            const int so = (kq ^ lm15) << 2;   // swizzled X float4 slot
#pragma unroll
            for (int g = 0; g < 2; ++g) {
                const float4 xv = *(const float4*)(xb + (g * 64 + l) * BK + so);
#pragma unroll
                for (int j = 0; j < 8; ++j) {
                    acc[g][j] = fmaf(xv.x, wv[j].x, acc[g][j]);
                    acc[g][j] = fmaf(xv.y, wv[j].y, acc[g][j]);
                    acc[g][j] = fmaf(xv.z, wv[j].z, acc[g][j]);
                    acc[g][j] = fmaf(xv.w, wv[j].w, acc[g][j]);
                }
            }
        }
    }

    float* dst = lp + (size_t)slice * TTOK * ENUM + (size_t)(T0 + l) * ENUM
               + eh * TE + E0;
#pragma unroll
    for (int g = 0; g < 2; ++g) {
        float* d = dst + (size_t)g * 64 * ENUM;
        *(float4*)(d + 0) = make_float4(acc[g][0], acc[g][1], acc[g][2], acc[g][3]);
        *(float4*)(d + 4) = make_float4(acc[g][4], acc[g][5], acc[g][6], acc[g][7]);
    }
#undef STAGE
}

// ---------------------------------------------------------------------------
// Kernel 2: thread-per-token router. 64 tokens/block, 256 blocks. (unchanged)
// ---------------------------------------------------------------------------
#define RTOK 64
__global__ __launch_bounds__(256)
void router_topk(const float* __restrict__ lp,
                 float* __restrict__ out_idx, float* __restrict__ out_w,
                 float* __restrict__ ssum_g, int* __restrict__ cnt_g) {
    __shared__ float Ls[RTOK * 67];
    __shared__ float s_m[RTOK], s_inv[RTOK];
    __shared__ float s_ssum[ENUM];
    __shared__ int   s_cnt[ENUM];

    const int tid = threadIdx.x;
    const int t0  = blockIdx.x * RTOK;
    if (tid < ENUM) { s_cnt[tid] = 0; s_ssum[tid] = 0.f; }

#pragma unroll
    for (int r = 0; r < 4; ++r) {
        const int q  = r * 256 + tid;
        const int t  = q >> 4, c4 = q & 15;
        const size_t base = (size_t)(t0 + t) * ENUM + c4 * 4;
        float4 v = *(const float4*)(lp + base);
#pragma unroll
        for (int h = 1; h < KSPLIT; ++h) {
            float4 u = *(const float4*)(lp + (size_t)h * TTOK * ENUM + base);
            v.x += u.x; v.y += u.y; v.z += u.z; v.w += u.w;
        }
        float* d = Ls + t * 67 + c4 * 4;
        d[0] = v.x; d[1] = v.y; d[2] = v.z; d[3] = v.w;
    }
    __syncthreads();

    if (tid < RTOK) {
        const float* row = Ls + tid * 67;

        float gm[GNUM];
#pragma unroll
        for (int g = 0; g < GNUM; ++g) {
            float mg = row[g * 8];
#pragma unroll
            for (int j = 1; j < 8; ++j) mg = fmaxf(mg, row[g * 8 + j]);
            gm[g] = mg;
        }
        float m = gm[0];
#pragma unroll
        for (int g = 1; g < GNUM; ++g) m = fmaxf(m, gm[g]);

        int selmask = 0;
#pragma unroll
        for (int g = 0; g < GNUM; ++g) {
            int rank = 0;
#pragma unroll
            for (int g2 = 0; g2 < GNUM; ++g2)
                rank += (gm[g2] > gm[g]) || (gm[g2] == gm[g] && g2 < g);
            selmask |= (rank < TGK) << g;
        }

        float v0=-1.f,v1=-1.f,v2=-1.f,v3=-1.f,v4=-1.f,v5=-1.f;
        float i0=0.f,i1=0.f,i2=0.f,i3=0.f,i4=0.f,i5=0.f;
        float s = 0.f;
#pragma unroll
        for (int e = 0; e < ENUM; ++e) {
            const float ex = __expf(row[e] - m);
            s += ex;
            const float cand = ((selmask >> (e >> 3)) & 1) ? ex : -1.0f;
            const float fe = (float)e;
            const bool b0 = cand > v0, b1 = cand > v1, b2 = cand > v2,
                       b3 = cand > v3, b4 = cand > v4, b5 = cand > v5;
            v5 = b4 ? v4 : (b5 ? cand : v5);  i5 = b4 ? i4 : (b5 ? fe : i5);
            v4 = b3 ? v3 : (b4 ? cand : v4);  i4 = b3 ? i3 : (b4 ? fe : i4);
            v3 = b2 ? v2 : (b3 ? cand : v3);  i3 = b2 ? i2 : (b3 ? fe : i3);
            v2 = b1 ? v1 : (b2 ? cand : v2);  i2 = b1 ? i1 : (b2 ? fe : i2);
            v1 = b0 ? v0 : (b1 ? cand : v1);  i1 = b0 ? i0 : (b1 ? fe : i1);
            v0 = b0 ? cand : v0;              i0 = b0 ? fe : i0;
        }
        const float invw = 1.0f / (v0 + v1 + v2 + v3 + v4 + v5);
        const int t = t0 + tid;
        float* oi = out_idx + (size_t)t * KTOP;
        float* ow = out_w   + (size_t)t * KTOP;
        oi[0]=i0; oi[1]=i1; oi[2]=i2; oi[3]=i3; oi[4]=i4; oi[5]=i5;
        ow[0]=v0*invw; ow[1]=v1*invw; ow[2]=v2*invw;
        ow[3]=v3*invw; ow[4]=v4*invw; ow[5]=v5*invw;

        atomicAdd(&s_cnt[(int)i0], 1); atomicAdd(&s_cnt[(int)i1], 1);
        atomicAdd(&s_cnt[(int)i2], 1); atomicAdd(&s_cnt[(int)i3], 1);
        atomicAdd(&s_cnt[(int)i4], 1); atomicAdd(&s_cnt[(int)i5], 1);
        s_m[tid] = m; s_inv[tid] = 1.0f / s;
    }
    __syncthreads();

    {
        const int e = tid & 63, strip = tid >> 6;
        float acc = 0.f;
#pragma unroll
        for (int i = 0; i < RTOK / 4; ++i) {
            const int t = strip * (RTOK / 4) + i;
            acc += __expf(Ls[t * 67 + e] - s_m[t]) * s_inv[t];
        }
        atomicAdd(&s_ssum[e], acc);
    }
    __syncthreads();

    const int b = t0 / SSEQ;
    if (tid < ENUM) {
        atomicAdd(&ssum_g[b * ENUM + tid], s_ssum[tid]);
        atomicAdd(&cnt_g[b * ENUM + tid], s_cnt[tid]);
    }
}

// ---------------------------------------------------------------------------
// Kernel 3: aux loss (1 block) (unchanged)
// ---------------------------------------------------------------------------
__global__ __launch_bounds__(256)
void aux_loss(const float* __restrict__ ssum_g, const int* __restrict__ cnt_g,
              float* __restrict__ out_aux) {
    const int tid = threadIdx.x;
    float v = (float)cnt_g[tid] * (float)ENUM / ((float)SSEQ * (float)KTOP)
            * (ssum_g[tid] / (float)SSEQ);
#pragma unroll
    for (int off = 32; off; off >>= 1) v += __shfl_xor(v, off);
    __shared__ float red[4];
    if ((tid & 63) == 0) red[tid >> 6] = v;
    __syncthreads();
    if (tid == 0)
        out_aux[0] = (red[0] + red[1] + red[2] + red[3]) * (ALPHAC / (float)BBATCH);
}

// ---------------------------------------------------------------------------
extern "C" void kernel_launch(void* const* d_in, const int* in_sizes, int n_in,
                              void* d_out, int out_size, void* d_ws, size_t ws_size,
                              hipStream_t stream) {
    const float* X = (const float*)d_in[0];   // [4,4096,4096] fp32
    const float* W = (const float*)d_in[1];   // [64,4096] fp32

    float* out     = (float*)d_out;
    float* out_idx = out;
    float* out_w   = out + (size_t)TTOK * KTOP;
    float* out_aux = out + (size_t)2 * TTOK * KTOP;

    float* lp     = (float*)d_ws;                        // [4][T][64] = 16 MiB
    float* Wp     = lp + (size_t)KSPLIT * TTOK * ENUM;   // [1024][64][4] = 1 MiB
    float* ssum_g = Wp + (size_t)HDIM * ENUM;            // [4][64]
    int*   cnt_g  = (int*)(ssum_g + BBATCH * ENUM);      // [4][64]

    hipMemsetAsync(ssum_g, 0, BBATCH * ENUM * (sizeof(float) + sizeof(int)), stream);

    pack_w<<<(HDIM / 4) * ENUM / 256, 256, 0, stream>>>(W, Wp);
    gate_gemm<<<(TTOK / TM) * 2 * KSPLIT, 256, 0, stream>>>(X, Wp, lp);
    router_topk<<<TTOK / RTOK, 256, 0, stream>>>(lp, out_idx, out_w, ssum_g, cnt_g);
    aux_loss<<<1, 256, 0, stream>>>(ssum_g, cnt_g, out_aux);
}